// Round 2
// baseline (24274.129 us; speedup 1.0000x reference)
//
#include <hip/hip_runtime.h>
#include <hip/hip_bf16.h>
#include <cstdint>
#include <cstddef>

#define NDIMC   128
#define DEPTHC  6
#define NPASSESC 4
#define NNODES  50000
#define NEDGES  800000
#define NODEIN  5
#define LNEPS   1e-5f

#define BM   64
#define LDP  68   // 64 + 4 pad: keeps float4 (16B) alignment, breaks worst bank conflicts

// ---------------------------------------------------------------------------
// ws layout (bytes) — total 256,000,004 B (~244 MiB)
#define H_OFF    0ull                          // h:   50000*128*4 = 25.6 MB fp32
#define AGG_OFF  25600000ull                   // agg: 25.6 MB fp32
#define E_OFF    51200000ull                   // e:   800000*128*2 = 204.8 MB bf16
#define FLAG_OFF 256000000ull

// ---------------------------------------------------------------------------
// 4-element vector load/store with storage-type conversion (compute is fp32)
__device__ __forceinline__ float4 mgn_ld4(const float* p) { return *(const float4*)p; }
__device__ __forceinline__ float4 mgn_ld4(const __hip_bfloat16* p) {
    uint2 u = *(const uint2*)p;
    float4 r;
    r.x = __uint_as_float(u.x << 16);
    r.y = __uint_as_float(u.x & 0xffff0000u);
    r.z = __uint_as_float(u.y << 16);
    r.w = __uint_as_float(u.y & 0xffff0000u);
    return r;
}
__device__ __forceinline__ unsigned mgn_bf16bits(float f) {
    unsigned x = __float_as_uint(f);
    return (x + 0x7fffu + ((x >> 16) & 1u)) >> 16;   // RNE
}
__device__ __forceinline__ void mgn_st4(float* p, float4 v) { *(float4*)p = v; }
__device__ __forceinline__ void mgn_st4(__hip_bfloat16* p, float4 v) {
    uint2 u;
    u.x = mgn_bf16bits(v.x) | (mgn_bf16bits(v.y) << 16);
    u.y = mgn_bf16bits(v.z) | (mgn_bf16bits(v.w) << 16);
    *(uint2*)p = u;
}

// ---------------------------------------------------------------------------
// Detect whether ij arrived as int64 (odd 32-bit words all zero) or int32.
// flag = 1 -> int32, flag = 0 -> int64
__global__ void mgn_detect_kernel(const int* __restrict__ ij, int* __restrict__ flag) {
    __shared__ int any;
    if (threadIdx.x == 0) any = 0;
    __syncthreads();
    if (ij[2 * threadIdx.x + 1] != 0) atomicOr(&any, 1);
    __syncthreads();
    if (threadIdx.x == 0) *flag = any;
}

__device__ __forceinline__ long mgn_load_idx(const int* __restrict__ ij, long pos, int is32) {
    if (is32) return (long)ij[pos];
    const long long* ij8 = (const long long*)ij;
    return (long)ij8[pos];
}

// ---------------------------------------------------------------------------
__global__ void mgn_encoder_kernel(const float* __restrict__ v,
                                   const float* __restrict__ encW,
                                   const float* __restrict__ encB,
                                   float* __restrict__ h) {
    int idx = blockIdx.x * blockDim.x + threadIdx.x;
    if (idx >= NNODES * NDIMC) return;
    int n = idx >> 7, d = idx & 127;
    float acc = encB[d];
#pragma unroll
    for (int k = 0; k < NODEIN; ++k)
        acc = fmaf(v[n * NODEIN + k], encW[k * NDIMC + d], acc);
    h[idx] = acc;
}

// e[e] = h[ij0[e]] - h[ij1[e]] (+ e_prev[e]) ; bf16 out
__global__ void mgn_gather_kernel(const float* __restrict__ h,
                                  const int* __restrict__ ij,
                                  const int* __restrict__ flag,
                                  __hip_bfloat16* __restrict__ eout, int addE) {
    int idx = blockIdx.x * blockDim.x + threadIdx.x;   // per 4 elements
    if (idx >= NEDGES * 32) return;
    int e = idx >> 5, q = idx & 31;
    int is32 = *flag;
    long i0 = mgn_load_idx(ij, e, is32);
    long i1 = mgn_load_idx(ij, (long)NEDGES + e, is32);
    const float4* h4 = (const float4*)h;
    float4 a = h4[i0 * 32 + q];
    float4 b = h4[i1 * 32 + q];
    float4 r;
    r.x = a.x - b.x; r.y = a.y - b.y; r.z = a.z - b.z; r.w = a.w - b.w;
    __hip_bfloat16* p = eout + (size_t)e * NDIMC + q * 4;
    if (addE) {
        float4 ep = mgn_ld4((const __hip_bfloat16*)p);
        r.x += ep.x; r.y += ep.y; r.z += ep.z; r.w += ep.w;
    }
    mgn_st4(p, r);
}

__global__ void mgn_scatter_kernel(const __hip_bfloat16* __restrict__ ebuf,
                                   const int* __restrict__ ij,
                                   const int* __restrict__ flag,
                                   float* __restrict__ agg) {
    long idx = (long)blockIdx.x * blockDim.x + threadIdx.x;  // per element
    if (idx >= (long)NEDGES * NDIMC) return;
    int e = (int)(idx >> 7), d = (int)(idx & 127);
    int is32 = *flag;
    long dst = mgn_load_idx(ij, (long)NEDGES + e, is32);
    unsigned short b = *(const unsigned short*)(ebuf + idx);
    float val = __uint_as_float(((unsigned)b) << 16);
    atomicAdd(&agg[dst * NDIMC + d], val);
}

__global__ void mgn_add_kernel(float* __restrict__ h, const float* __restrict__ agg) {
    int idx = blockIdx.x * blockDim.x + threadIdx.x;  // per float4
    if (idx >= NNODES * 32) return;
    float4 a = ((float4*)h)[idx];
    float4 b = ((const float4*)agg)[idx];
    a.x += b.x; a.y += b.y; a.z += b.z; a.w += b.w;
    ((float4*)h)[idx] = a;
}

__global__ void mgn_decoder_kernel(const float* __restrict__ h,
                                   const float* __restrict__ decW,
                                   const float* __restrict__ decB,
                                   float* __restrict__ out) {
    int idx = blockIdx.x * blockDim.x + threadIdx.x;
    if (idx >= NNODES * NODEIN) return;
    int n = idx / NODEIN, j = idx % NODEIN;
    float acc = decB[j];
#pragma unroll 8
    for (int k = 0; k < NDIMC; ++k)
        acc = fmaf(h[n * NDIMC + k], decW[k * NODEIN + j], acc);
    out[idx] = acc;
}

// ---------------------------------------------------------------------------
// Fused 6-deep residual MLP over a 64-row tile, fp32 vector math.
// Thread (cg = t&31, rg = t>>5) owns cols c0..c0+3, rows r0..r0+7.
__device__ __forceinline__ void mgn_gemm(const float (&xs)[NDIMC][LDP],
                                         const float* __restrict__ Wg,
                                         int c0, int r0, float acc[8][4]) {
#pragma unroll
    for (int i = 0; i < 8; ++i) {
        acc[i][0] = 0.f; acc[i][1] = 0.f; acc[i][2] = 0.f; acc[i][3] = 0.f;
    }
#pragma unroll 4
    for (int k = 0; k < NDIMC; ++k) {
        const float4 w  = *(const float4*)(Wg + k * NDIMC + c0);
        const float4 xa = *(const float4*)&xs[k][r0];
        const float4 xb = *(const float4*)&xs[k][r0 + 4];
        const float wv[4] = {w.x, w.y, w.z, w.w};
        const float xv[8] = {xa.x, xa.y, xa.z, xa.w, xb.x, xb.y, xb.z, xb.w};
#pragma unroll
        for (int i = 0; i < 8; ++i)
#pragma unroll
            for (int j = 0; j < 4; ++j)
                acc[i][j] = fmaf(xv[i], wv[j], acc[i][j]);
    }
}

template <typename T>
__global__ __launch_bounds__(256, 2) void mgn_mlp6_kernel(
    T* __restrict__ X, int nrows,
    const float* __restrict__ W1, const float* __restrict__ B1,
    const float* __restrict__ W2, const float* __restrict__ B2,
    const float* __restrict__ G,  const float* __restrict__ BT) {
    __shared__ float xs[NDIMC][LDP];

    const int t  = threadIdx.x;
    const int cg = t & 31;
    const int rg = t >> 5;
    const int c0 = cg * 4;
    const int r0 = rg * 8;
    const long rowbase = (long)blockIdx.x * BM;

    // Load 64x128 tile, transposed: xs[k][r] = X[rowbase+r][k]
#pragma unroll
    for (int rr = 0; rr < 8; ++rr) {
        int row = rg + rr * 8;
        long grow = rowbase + row;
        float4 v = make_float4(0.f, 0.f, 0.f, 0.f);
        if (grow < nrows) v = mgn_ld4(X + grow * NDIMC + cg * 4);
        xs[c0 + 0][row] = v.x; xs[c0 + 1][row] = v.y;
        xs[c0 + 2][row] = v.z; xs[c0 + 3][row] = v.w;
    }
    __syncthreads();

    // residual patch in registers
    float xres[8][4];
#pragma unroll
    for (int j = 0; j < 4; ++j) {
        float4 a = *(const float4*)&xs[c0 + j][r0];
        float4 b = *(const float4*)&xs[c0 + j][r0 + 4];
        xres[0][j] = a.x; xres[1][j] = a.y; xres[2][j] = a.z; xres[3][j] = a.w;
        xres[4][j] = b.x; xres[5][j] = b.y; xres[6][j] = b.z; xres[7][j] = b.w;
    }

    for (int d = 0; d < DEPTHC; ++d) {
        const float* Wg1 = W1 + (size_t)d * NDIMC * NDIMC;
        const float* Wg2 = W2 + (size_t)d * NDIMC * NDIMC;
        float acc[8][4];

        // GEMM1: h1 = relu(x @ W1 + b1)
        mgn_gemm(xs, Wg1, c0, r0, acc);
        {
            float4 bv = *(const float4*)(B1 + d * NDIMC + c0);
            float bj[4] = {bv.x, bv.y, bv.z, bv.w};
            __syncthreads();   // all GEMM1 reads of xs done
#pragma unroll
            for (int j = 0; j < 4; ++j) {
                float4 h0, h1;
                h0.x = fmaxf(acc[0][j] + bj[j], 0.f);
                h0.y = fmaxf(acc[1][j] + bj[j], 0.f);
                h0.z = fmaxf(acc[2][j] + bj[j], 0.f);
                h0.w = fmaxf(acc[3][j] + bj[j], 0.f);
                h1.x = fmaxf(acc[4][j] + bj[j], 0.f);
                h1.y = fmaxf(acc[5][j] + bj[j], 0.f);
                h1.z = fmaxf(acc[6][j] + bj[j], 0.f);
                h1.w = fmaxf(acc[7][j] + bj[j], 0.f);
                *(float4*)&xs[c0 + j][r0]     = h0;   // xs now holds h1 (transposed)
                *(float4*)&xs[c0 + j][r0 + 4] = h1;
            }
            __syncthreads();
        }

        // GEMM2: h2 = relu(h1 @ W2 + b2)
        mgn_gemm(xs, Wg2, c0, r0, acc);
        {
            float4 bv = *(const float4*)(B2 + d * NDIMC + c0);
            float bj[4] = {bv.x, bv.y, bv.z, bv.w};
#pragma unroll
            for (int i = 0; i < 8; ++i)
#pragma unroll
                for (int j = 0; j < 4; ++j)
                    acc[i][j] = fmaxf(acc[i][j] + bj[j], 0.f);
        }

        // LayerNorm over 128 cols (rows live on 32 contiguous lanes), residual add
        {
            float4 gv  = *(const float4*)(G  + d * NDIMC + c0);
            float4 btv = *(const float4*)(BT + d * NDIMC + c0);
            float gj[4]  = {gv.x, gv.y, gv.z, gv.w};
            float btj[4] = {btv.x, btv.y, btv.z, btv.w};
#pragma unroll
            for (int i = 0; i < 8; ++i) {
                float s = acc[i][0] + acc[i][1] + acc[i][2] + acc[i][3];
                s += __shfl_xor(s, 1);  s += __shfl_xor(s, 2);
                s += __shfl_xor(s, 4);  s += __shfl_xor(s, 8);
                s += __shfl_xor(s, 16);
                float mean = s * 0.0078125f;
                float d0 = acc[i][0] - mean, d1 = acc[i][1] - mean;
                float d2 = acc[i][2] - mean, d3 = acc[i][3] - mean;
                float ss = d0 * d0 + d1 * d1 + d2 * d2 + d3 * d3;
                ss += __shfl_xor(ss, 1);  ss += __shfl_xor(ss, 2);
                ss += __shfl_xor(ss, 4);  ss += __shfl_xor(ss, 8);
                ss += __shfl_xor(ss, 16);
                float rstd = rsqrtf(ss * 0.0078125f + LNEPS);
                xres[i][0] += fmaf(d0 * rstd, gj[0], btj[0]);
                xres[i][1] += fmaf(d1 * rstd, gj[1], btj[1]);
                xres[i][2] += fmaf(d2 * rstd, gj[2], btj[2]);
                xres[i][3] += fmaf(d3 * rstd, gj[3], btj[3]);
            }
        }

        __syncthreads();   // all GEMM2 reads of xs done
#pragma unroll
        for (int j = 0; j < 4; ++j) {
            float4 a = {xres[0][j], xres[1][j], xres[2][j], xres[3][j]};
            float4 b = {xres[4][j], xres[5][j], xres[6][j], xres[7][j]};
            *(float4*)&xs[c0 + j][r0]     = a;
            *(float4*)&xs[c0 + j][r0 + 4] = b;
        }
        __syncthreads();
    }

    // write back (with storage-type conversion)
#pragma unroll
    for (int rr = 0; rr < 8; ++rr) {
        int row = rg + rr * 8;
        long grow = rowbase + row;
        if (grow < nrows) {
            float4 v = {xs[c0 + 0][row], xs[c0 + 1][row],
                        xs[c0 + 2][row], xs[c0 + 3][row]};
            mgn_st4(X + grow * NDIMC + cg * 4, v);
        }
    }
}

// ---------------------------------------------------------------------------
extern "C" void kernel_launch(void* const* d_in, const int* in_sizes, int n_in,
                              void* d_out, int out_size, void* d_ws, size_t ws_size,
                              hipStream_t stream) {
    const float* v    = (const float*)d_in[0];
    const int*   ij   = (const int*)d_in[1];
    const float* encW = (const float*)d_in[2];
    const float* encB = (const float*)d_in[3];
    const float* eW1  = (const float*)d_in[4];
    const float* eB1  = (const float*)d_in[5];
    const float* eW2  = (const float*)d_in[6];
    const float* eB2  = (const float*)d_in[7];
    const float* eG   = (const float*)d_in[8];
    const float* eBT  = (const float*)d_in[9];
    const float* nW1  = (const float*)d_in[10];
    const float* nB1  = (const float*)d_in[11];
    const float* nW2  = (const float*)d_in[12];
    const float* nB2  = (const float*)d_in[13];
    const float* nG   = (const float*)d_in[14];
    const float* nBT  = (const float*)d_in[15];
    const float* decW = (const float*)d_in[16];
    const float* decB = (const float*)d_in[17];
    float* out = (float*)d_out;

    char* ws = (char*)d_ws;
    float*          h    = (float*)(ws + H_OFF);
    float*          agg  = (float*)(ws + AGG_OFF);
    __hip_bfloat16* ebuf = (__hip_bfloat16*)(ws + E_OFF);
    int*            flag = (int*)(ws + FLAG_OFF);

    mgn_detect_kernel<<<1, 256, 0, stream>>>(ij, flag);
    mgn_encoder_kernel<<<(NNODES * NDIMC + 255) / 256, 256, 0, stream>>>(v, encW, encB, h);

    for (int p = 0; p < NPASSESC; ++p) {
        mgn_gather_kernel<<<(NEDGES * 32 + 255) / 256, 256, 0, stream>>>(
            h, ij, flag, ebuf, p > 0 ? 1 : 0);
        mgn_mlp6_kernel<__hip_bfloat16><<<NEDGES / BM, 256, 0, stream>>>(
            ebuf, NEDGES, eW1, eB1, eW2, eB2, eG, eBT);
        hipMemsetAsync(agg, 0, (size_t)NNODES * NDIMC * sizeof(float), stream);
        mgn_scatter_kernel<<<(int)(((long)NEDGES * NDIMC + 255) / 256), 256, 0, stream>>>(
            ebuf, ij, flag, agg);
        mgn_add_kernel<<<(NNODES * 32 + 255) / 256, 256, 0, stream>>>(h, agg);
        mgn_mlp6_kernel<float><<<(NNODES + BM - 1) / BM, 256, 0, stream>>>(
            h, NNODES, nW1, nB1, nW2, nB2, nG, nBT);
    }

    mgn_decoder_kernel<<<(NNODES * NODEIN + 255) / 256, 256, 0, stream>>>(h, decW, decB, out);
}

// Round 3
// 5622.324 us; speedup vs baseline: 4.3175x; 4.3175x over previous
//
#include <hip/hip_runtime.h>
#include <hip/hip_bf16.h>
#include <cstdint>
#include <cstddef>

#define NDIMC   128
#define DEPTHC  6
#define NPASSESC 4
#define NNODES  50000
#define NEDGES  800000
#define NODEIN  5
#define LNEPS   1e-5f

// ---------------------------------------------------------------------------
// ws layout (bytes) — total 231,186,436 B (< proven-safe 256,000,004)
#define H_OFF    0ull                     // h:    50000*128*4  = 25.6 MB fp32
#define E_OFF    25600000ull              // e:    800000*128*2 = 204.8 MB bf16
#define PW_OFF   230400000ull             // packed weights: 4 * 196,608 B bf16
#define FLAG_OFF 231186432ull
#define PWMAT    98304                    // elements per packed matrix (6*8*4*64*8)

typedef __attribute__((ext_vector_type(8))) short mgn_sh8;
typedef __attribute__((ext_vector_type(4))) float mgn_f32x4;

// ---------------------------------------------------------------------------
__device__ __forceinline__ unsigned mgn_bf16bits(float f) {
    unsigned x = __float_as_uint(f);
    return (x + 0x7fffu + ((x >> 16) & 1u)) >> 16;   // RNE
}
__device__ __forceinline__ float4 mgn_ld4(const float* p) { return *(const float4*)p; }
__device__ __forceinline__ float4 mgn_ld4(const __hip_bfloat16* p) {
    uint2 u = *(const uint2*)p;
    float4 r;
    r.x = __uint_as_float(u.x << 16);
    r.y = __uint_as_float(u.x & 0xffff0000u);
    r.z = __uint_as_float(u.y << 16);
    r.w = __uint_as_float(u.y & 0xffff0000u);
    return r;
}
__device__ __forceinline__ void mgn_st4(__hip_bfloat16* p, float4 v) {
    uint2 u;
    u.x = mgn_bf16bits(v.x) | (mgn_bf16bits(v.y) << 16);
    u.y = mgn_bf16bits(v.z) | (mgn_bf16bits(v.w) << 16);
    *(uint2*)p = u;
}
__device__ __forceinline__ float mgn_ldx(const float* p) { return *p; }
__device__ __forceinline__ float mgn_ldx(const unsigned short* p) {
    return __uint_as_float(((unsigned)*p) << 16);
}
__device__ __forceinline__ void mgn_stx(float* p, float v) { *p = v; }
__device__ __forceinline__ void mgn_stx(unsigned short* p, float v) {
    *p = (unsigned short)mgn_bf16bits(v);
}

// ---------------------------------------------------------------------------
// flag = 1 -> ij is int32, flag = 0 -> ij is int64
__global__ void mgn_detect_kernel(const int* __restrict__ ij, int* __restrict__ flag) {
    __shared__ int any;
    if (threadIdx.x == 0) any = 0;
    __syncthreads();
    if (ij[2 * threadIdx.x + 1] != 0) atomicOr(&any, 1);
    __syncthreads();
    if (threadIdx.x == 0) *flag = any;
}

__device__ __forceinline__ long mgn_load_idx(const int* __restrict__ ij, long pos, int is32) {
    if (is32) return (long)ij[pos];
    const long long* ij8 = (const long long*)ij;
    return (long)ij8[pos];
}

// ---------------------------------------------------------------------------
// Pack fp32 row-major W[d][k][n] into MFMA B-fragment order:
// element i = (((d*8+t)*4+s)*64+lane)*8+j  holds  W[d][s*32+(lane>>4)*8+j][t*16+(lane&15)]
__global__ void mgn_pack_kernel(const float* __restrict__ W, unsigned short* __restrict__ pw) {
    int i = blockIdx.x * blockDim.x + threadIdx.x;
    if (i >= PWMAT) return;
    int j    = i & 7;
    int lane = (i >> 3) & 63;
    int s    = (i >> 9) & 3;
    int t    = (i >> 11) & 7;
    int d    = i >> 14;
    int k = s * 32 + (lane >> 4) * 8 + j;
    int n = t * 16 + (lane & 15);
    pw[i] = (unsigned short)mgn_bf16bits(W[(d * NDIMC + k) * NDIMC + n]);
}

// ---------------------------------------------------------------------------
__global__ void mgn_encoder_kernel(const float* __restrict__ v,
                                   const float* __restrict__ encW,
                                   const float* __restrict__ encB,
                                   float* __restrict__ h) {
    int idx = blockIdx.x * blockDim.x + threadIdx.x;
    if (idx >= NNODES * NDIMC) return;
    int n = idx >> 7, d = idx & 127;
    float acc = encB[d];
#pragma unroll
    for (int k = 0; k < NODEIN; ++k)
        acc = fmaf(v[n * NODEIN + k], encW[k * NDIMC + d], acc);
    h[idx] = acc;
}

// e[e] = h[ij0[e]] - h[ij1[e]] (+ e_prev[e]) ; bf16 out
__global__ void mgn_gather_kernel(const float* __restrict__ h,
                                  const int* __restrict__ ij,
                                  const int* __restrict__ flag,
                                  __hip_bfloat16* __restrict__ eout, int addE) {
    int idx = blockIdx.x * blockDim.x + threadIdx.x;   // per 4 elements
    if (idx >= NEDGES * 32) return;
    int e = idx >> 5, q = idx & 31;
    int is32 = *flag;
    long i0 = mgn_load_idx(ij, e, is32);
    long i1 = mgn_load_idx(ij, (long)NEDGES + e, is32);
    const float4* h4 = (const float4*)h;
    float4 a = h4[i0 * 32 + q];
    float4 b = h4[i1 * 32 + q];
    float4 r;
    r.x = a.x - b.x; r.y = a.y - b.y; r.z = a.z - b.z; r.w = a.w - b.w;
    __hip_bfloat16* p = eout + (size_t)e * NDIMC + q * 4;
    if (addE) {
        float4 ep = mgn_ld4((const __hip_bfloat16*)p);
        r.x += ep.x; r.y += ep.y; r.z += ep.z; r.w += ep.w;
    }
    mgn_st4(p, r);
}

// scatter-add edges straight into h (h already consumed by gather this pass)
__global__ void mgn_scatter_kernel(const __hip_bfloat16* __restrict__ ebuf,
                                   const int* __restrict__ ij,
                                   const int* __restrict__ flag,
                                   float* __restrict__ h) {
    long idx = (long)blockIdx.x * blockDim.x + threadIdx.x;  // per element
    if (idx >= (long)NEDGES * NDIMC) return;
    int e = (int)(idx >> 7), d = (int)(idx & 127);
    int is32 = *flag;
    long dst = mgn_load_idx(ij, (long)NEDGES + e, is32);
    unsigned short b = *(const unsigned short*)(ebuf + idx);
    float val = __uint_as_float(((unsigned)b) << 16);
    atomicAdd(&h[dst * NDIMC + d], val);
}

__global__ void mgn_decoder_kernel(const float* __restrict__ h,
                                   const float* __restrict__ decW,
                                   const float* __restrict__ decB,
                                   float* __restrict__ out) {
    int idx = blockIdx.x * blockDim.x + threadIdx.x;
    if (idx >= NNODES * NODEIN) return;
    int n = idx / NODEIN, j = idx % NODEIN;
    float acc = decB[j];
#pragma unroll 8
    for (int k = 0; k < NDIMC; ++k)
        acc = fmaf(h[n * NDIMC + k], decW[k * NODEIN + j], acc);
    out[idx] = acc;
}

// ---------------------------------------------------------------------------
// Fused 6-deep residual MLP, bf16 MFMA core, fp32 residual/LN.
// Block = 256 threads = 4 waves; wave w owns rows w*16..w*16+15 of a 64-row
// tile (wave-private in LDS -> NO __syncthreads anywhere).
// Layouts (verified): A-frag A[m=lane&15][k=quad*8+j]; B-frag B[k=quad*8+j][n=lane&15];
// C/D row=quad*4+reg, col=lane&15.
template <typename T>
__global__ __launch_bounds__(256, 3) void mgn_mlp6_mfma_kernel(
    T* __restrict__ X, int nrows,
    const unsigned short* __restrict__ PW1,
    const unsigned short* __restrict__ PW2,
    const float* __restrict__ B1, const float* __restrict__ B2,
    const float* __restrict__ G,  const float* __restrict__ BT)
{
    __shared__ unsigned short xl[64 * 136];   // row stride 136 bf16 = 272 B (bank-spread)
    const int tid = threadIdx.x;
    const int w   = tid >> 6;
    const int l   = tid & 63;
    const int q   = l >> 4;
    const int lm  = l & 15;
    const int rloc = w * 16 + q * 4;          // first of this lane's 4 C-rows (local)
    const long rowbase = (long)blockIdx.x * 64;

    // Load tile: xres fp32 regs (C layout) + LDS bf16 (A-operand source)
    float xres[4][8];
#pragma unroll
    for (int r = 0; r < 4; ++r) {
        long gr = rowbase + rloc + r;
        bool ok = gr < nrows;
#pragma unroll
        for (int t = 0; t < 8; ++t) {
            float v = ok ? mgn_ldx(X + gr * NDIMC + t * 16 + lm) : 0.f;
            xres[r][t] = v;
            xl[(rloc + r) * 136 + t * 16 + lm] = (unsigned short)mgn_bf16bits(v);
        }
    }

    const int arow = (w * 16 + lm) * 136;     // A-frag row base (wave-private)

    for (int d = 0; d < DEPTHC; ++d) {
        float b1v[8];
#pragma unroll
        for (int t = 0; t < 8; ++t) b1v[t] = B1[d * NDIMC + t * 16 + lm];

        // ---- GEMM1: h1 = relu(x @ W1 + b1)
        mgn_sh8 a[4];
#pragma unroll
        for (int s = 0; s < 4; ++s)
            a[s] = *(const mgn_sh8*)&xl[arow + s * 32 + q * 8];
        mgn_f32x4 acc[8];
#pragma unroll
        for (int t = 0; t < 8; ++t) acc[t] = (mgn_f32x4){0.f, 0.f, 0.f, 0.f};
        const unsigned short* p1 = PW1 + (size_t)d * 16384 + l * 8;
#pragma unroll
        for (int t = 0; t < 8; ++t)
#pragma unroll
            for (int s = 0; s < 4; ++s) {
                mgn_sh8 b = *(const mgn_sh8*)(p1 + (t * 4 + s) * 512);
                acc[t] = __builtin_amdgcn_mfma_f32_16x16x32_bf16(a[s], b, acc[t], 0, 0, 0);
            }
        // h1 -> LDS (own rows only; in-wave RAW ordered by lgkmcnt)
#pragma unroll
        for (int t = 0; t < 8; ++t)
#pragma unroll
            for (int r = 0; r < 4; ++r) {
                float hv = fmaxf(acc[t][r] + b1v[t], 0.f);
                xl[(rloc + r) * 136 + t * 16 + lm] = (unsigned short)mgn_bf16bits(hv);
            }

        float b2v[8], gv[8], btv[8];
#pragma unroll
        for (int t = 0; t < 8; ++t) {
            b2v[t] = B2[d * NDIMC + t * 16 + lm];
            gv[t]  = G [d * NDIMC + t * 16 + lm];
            btv[t] = BT[d * NDIMC + t * 16 + lm];
        }

        // ---- GEMM2: h2 = relu(h1 @ W2 + b2)
#pragma unroll
        for (int s = 0; s < 4; ++s)
            a[s] = *(const mgn_sh8*)&xl[arow + s * 32 + q * 8];
#pragma unroll
        for (int t = 0; t < 8; ++t) acc[t] = (mgn_f32x4){0.f, 0.f, 0.f, 0.f};
        const unsigned short* p2 = PW2 + (size_t)d * 16384 + l * 8;
#pragma unroll
        for (int t = 0; t < 8; ++t)
#pragma unroll
            for (int s = 0; s < 4; ++s) {
                mgn_sh8 b = *(const mgn_sh8*)(p2 + (t * 4 + s) * 512);
                acc[t] = __builtin_amdgcn_mfma_f32_16x16x32_bf16(a[s], b, acc[t], 0, 0, 0);
            }

        // ---- bias2+relu, LayerNorm over 128 cols, residual add, write new x
#pragma unroll
        for (int r = 0; r < 4; ++r) {
            float sum = 0.f;
#pragma unroll
            for (int t = 0; t < 8; ++t) sum += fmaxf(acc[t][r] + b2v[t], 0.f);
            sum += __shfl_xor(sum, 1); sum += __shfl_xor(sum, 2);
            sum += __shfl_xor(sum, 4); sum += __shfl_xor(sum, 8);
            float mean = sum * 0.0078125f;
            float ss = 0.f;
#pragma unroll
            for (int t = 0; t < 8; ++t) {
                float dt = fmaxf(acc[t][r] + b2v[t], 0.f) - mean;
                ss += dt * dt;
            }
            ss += __shfl_xor(ss, 1); ss += __shfl_xor(ss, 2);
            ss += __shfl_xor(ss, 4); ss += __shfl_xor(ss, 8);
            float rstd = rsqrtf(ss * 0.0078125f + LNEPS);
#pragma unroll
            for (int t = 0; t < 8; ++t) {
                float dt = fmaxf(acc[t][r] + b2v[t], 0.f) - mean;
                float xn = xres[r][t] + fmaf(dt * rstd, gv[t], btv[t]);
                xres[r][t] = xn;
                xl[(rloc + r) * 136 + t * 16 + lm] = (unsigned short)mgn_bf16bits(xn);
            }
        }
    }

    // store (residual stream at full storage precision)
#pragma unroll
    for (int r = 0; r < 4; ++r) {
        long gr = rowbase + rloc + r;
        if (gr < nrows) {
#pragma unroll
            for (int t = 0; t < 8; ++t)
                mgn_stx(X + gr * NDIMC + t * 16 + lm, xres[r][t]);
        }
    }
}

// ---------------------------------------------------------------------------
extern "C" void kernel_launch(void* const* d_in, const int* in_sizes, int n_in,
                              void* d_out, int out_size, void* d_ws, size_t ws_size,
                              hipStream_t stream) {
    const float* v    = (const float*)d_in[0];
    const int*   ij   = (const int*)d_in[1];
    const float* encW = (const float*)d_in[2];
    const float* encB = (const float*)d_in[3];
    const float* eW1  = (const float*)d_in[4];
    const float* eB1  = (const float*)d_in[5];
    const float* eW2  = (const float*)d_in[6];
    const float* eB2  = (const float*)d_in[7];
    const float* eG   = (const float*)d_in[8];
    const float* eBT  = (const float*)d_in[9];
    const float* nW1  = (const float*)d_in[10];
    const float* nB1  = (const float*)d_in[11];
    const float* nW2  = (const float*)d_in[12];
    const float* nB2  = (const float*)d_in[13];
    const float* nG   = (const float*)d_in[14];
    const float* nBT  = (const float*)d_in[15];
    const float* decW = (const float*)d_in[16];
    const float* decB = (const float*)d_in[17];
    float* out = (float*)d_out;

    char* ws = (char*)d_ws;
    float*          h    = (float*)(ws + H_OFF);
    __hip_bfloat16* ebuf = (__hip_bfloat16*)(ws + E_OFF);
    unsigned short* pw   = (unsigned short*)(ws + PW_OFF);
    int*            flag = (int*)(ws + FLAG_OFF);

    mgn_detect_kernel<<<1, 256, 0, stream>>>(ij, flag);
    mgn_pack_kernel<<<(PWMAT + 255) / 256, 256, 0, stream>>>(eW1, pw + 0 * PWMAT);
    mgn_pack_kernel<<<(PWMAT + 255) / 256, 256, 0, stream>>>(eW2, pw + 1 * PWMAT);
    mgn_pack_kernel<<<(PWMAT + 255) / 256, 256, 0, stream>>>(nW1, pw + 2 * PWMAT);
    mgn_pack_kernel<<<(PWMAT + 255) / 256, 256, 0, stream>>>(nW2, pw + 3 * PWMAT);
    mgn_encoder_kernel<<<(NNODES * NDIMC + 255) / 256, 256, 0, stream>>>(v, encW, encB, h);

    for (int p = 0; p < NPASSESC; ++p) {
        mgn_gather_kernel<<<(NEDGES * 32 + 255) / 256, 256, 0, stream>>>(
            h, ij, flag, ebuf, p > 0 ? 1 : 0);
        mgn_mlp6_mfma_kernel<unsigned short><<<NEDGES / 64, 256, 0, stream>>>(
            (unsigned short*)ebuf, NEDGES, pw + 0 * PWMAT, pw + 1 * PWMAT, eB1, eB2, eG, eBT);
        mgn_scatter_kernel<<<(int)(((long)NEDGES * NDIMC + 255) / 256), 256, 0, stream>>>(
            ebuf, ij, flag, h);
        mgn_mlp6_mfma_kernel<float><<<(NNODES + 63) / 64, 256, 0, stream>>>(
            h, NNODES, pw + 2 * PWMAT, pw + 3 * PWMAT, nB1, nB2, nG, nBT);
    }

    mgn_decoder_kernel<<<(NNODES * NODEIN + 255) / 256, 256, 0, stream>>>(h, decW, decB, out);
}

// Round 4
// 5354.169 us; speedup vs baseline: 4.5337x; 1.0501x over previous
//
#include <hip/hip_runtime.h>
#include <hip/hip_bf16.h>
#include <cstdint>
#include <cstddef>

#define NDIMC   128
#define DEPTHC  6
#define NPASSESC 4
#define NNODES  50000
#define NEDGES  800000
#define NODEIN  5
#define LNEPS   1e-5f

// ---------------------------------------------------------------------------
// ws layout (bytes) — identical to round-3 proven-safe layout
#define H_OFF    0ull                     // h:    50000*128*4  = 25.6 MB fp32
#define E_OFF    25600000ull              // e:    800000*128*2 = 204.8 MB bf16
#define PW_OFF   230400000ull             // packed weights: 4 * 196,608 B bf16
#define FLAG_OFF 231186432ull
#define PWMAT    98304                    // elements per packed matrix

typedef __attribute__((ext_vector_type(8))) short mgn_sh8;
typedef __attribute__((ext_vector_type(4))) float mgn_f32x4;

// ---------------------------------------------------------------------------
__device__ __forceinline__ unsigned mgn_bf16bits(float f) {
    unsigned x = __float_as_uint(f);
    return (x + 0x7fffu + ((x >> 16) & 1u)) >> 16;   // RNE
}
// packed pair convert (v_cvt_pk_bf16_f32 on gfx950): low short = a
__device__ __forceinline__ unsigned mgn_pk(float a, float b) {
    __hip_bfloat162 t = __float22bfloat162_rn(make_float2(a, b));
    union { __hip_bfloat162 h; unsigned u; } c; c.h = t; return c.u;
}

// ---------------------------------------------------------------------------
// flag = 1 -> ij is int32, flag = 0 -> ij is int64
__global__ void mgn_detect_kernel(const int* __restrict__ ij, int* __restrict__ flag) {
    __shared__ int any;
    if (threadIdx.x == 0) any = 0;
    __syncthreads();
    if (ij[2 * threadIdx.x + 1] != 0) atomicOr(&any, 1);
    __syncthreads();
    if (threadIdx.x == 0) *flag = any;
}

__device__ __forceinline__ long mgn_load_idx(const int* __restrict__ ij, long pos, int is32) {
    if (is32) return (long)ij[pos];
    const long long* ij8 = (const long long*)ij;
    return (long)ij8[pos];
}

// ---------------------------------------------------------------------------
// Pack fp32 row-major W[d][k][n] into MFMA B-fragment order with REMAPPED
// output columns: B-tile t, lane holds  k = s*32+(lane>>4)*8+j,
// n_global = (lane&15)*8 + t   (so C/D lane lm owns 8 consecutive cols lm*8..+7)
__global__ void mgn_pack_kernel(const float* __restrict__ W, unsigned short* __restrict__ pw) {
    int i = blockIdx.x * blockDim.x + threadIdx.x;
    if (i >= PWMAT) return;
    int j    = i & 7;
    int lane = (i >> 3) & 63;
    int s    = (i >> 9) & 3;
    int t    = (i >> 11) & 7;
    int d    = i >> 14;
    int k = s * 32 + (lane >> 4) * 8 + j;
    int n = (lane & 15) * 8 + t;
    pw[i] = (unsigned short)mgn_bf16bits(W[(d * NDIMC + k) * NDIMC + n]);
}

// ---------------------------------------------------------------------------
__global__ void mgn_encoder_kernel(const float* __restrict__ v,
                                   const float* __restrict__ encW,
                                   const float* __restrict__ encB,
                                   float* __restrict__ h) {
    int idx = blockIdx.x * blockDim.x + threadIdx.x;
    if (idx >= NNODES * NDIMC) return;
    int n = idx >> 7, d = idx & 127;
    float acc = encB[d];
#pragma unroll
    for (int k = 0; k < NODEIN; ++k)
        acc = fmaf(v[n * NODEIN + k], encW[k * NDIMC + d], acc);
    h[idx] = acc;
}

// scatter-add edges straight into h (h already consumed by edge-MLP gather)
__global__ void mgn_scatter_kernel(const unsigned short* __restrict__ ebuf,
                                   const int* __restrict__ ij,
                                   const int* __restrict__ flag,
                                   float* __restrict__ h) {
    long idx = (long)blockIdx.x * blockDim.x + threadIdx.x;  // per element
    if (idx >= (long)NEDGES * NDIMC) return;
    int e = (int)(idx >> 7), d = (int)(idx & 127);
    int is32 = *flag;
    long dst = mgn_load_idx(ij, (long)NEDGES + e, is32);
    unsigned short b = ebuf[idx];
    float val = __uint_as_float(((unsigned)b) << 16);
    atomicAdd(&h[dst * NDIMC + d], val);
}

__global__ void mgn_decoder_kernel(const float* __restrict__ h,
                                   const float* __restrict__ decW,
                                   const float* __restrict__ decB,
                                   float* __restrict__ out) {
    int idx = blockIdx.x * blockDim.x + threadIdx.x;
    if (idx >= NNODES * NODEIN) return;
    int n = idx / NODEIN, j = idx % NODEIN;
    float acc = decB[j];
#pragma unroll 8
    for (int k = 0; k < NDIMC; ++k)
        acc = fmaf(h[n * NDIMC + k], decW[k * NODEIN + j], acc);
    out[idx] = acc;
}

// ---------------------------------------------------------------------------
// Fused 6-deep residual MLP, bf16 MFMA core, fp32 residual/LN.
// Block = 4 waves; wave w owns rows w*16..w*16+15 (wave-private: no barriers).
// Column remap: lane lm owns global cols lm*8..lm*8+7 (contiguous -> b128 LDS
// ops, dwordx4 global ops, cvt_pk converts).
// MODE 1 = edge: gathers x = h[i0]-h[i1] (+ e_prev), writes e (bf16).
// MODE 0 = node: x = h (fp32 in/out; scatter already added into h).
template <int MODE>
__global__ __launch_bounds__(256, 3) void mgn_mlp6_mfma_kernel(
    float* __restrict__ Xf,               // node: h
    unsigned short* __restrict__ Eb,      // edge: e
    const float* __restrict__ H,          // edge: h for gather
    const int* __restrict__ ij,
    const int* __restrict__ flag,
    int addE, int nrows,
    const unsigned short* __restrict__ PW1,
    const unsigned short* __restrict__ PW2,
    const float* __restrict__ B1, const float* __restrict__ B2,
    const float* __restrict__ G,  const float* __restrict__ BT)
{
    __shared__ unsigned short xl[64 * 136];   // row stride 136 shorts (272 B)
    const int tid = threadIdx.x;
    const int w   = tid >> 6;
    const int l   = tid & 63;
    const int q   = l >> 4;
    const int lm  = l & 15;
    const int rloc = w * 16 + q * 4;          // first of this lane's 4 C-rows
    const int ct   = lm * 8;                  // first of this lane's 8 cols
    const long rowbase = (long)blockIdx.x * 64;

    const int is32 = (MODE == 1) ? *flag : 0;

    // ---- tile load: xres fp32 regs (C layout) + LDS bf16 (A-operand source)
    float xres[4][8];
#pragma unroll
    for (int r = 0; r < 4; ++r) {
        long gr = rowbase + rloc + r;
        bool ok = gr < nrows;
        float xv[8];
        if (MODE == 1) {
            if (ok) {
                long i0 = mgn_load_idx(ij, gr, is32);
                long i1 = mgn_load_idx(ij, (long)NEDGES + gr, is32);
                const float* p0 = H + i0 * NDIMC + ct;
                const float* p1 = H + i1 * NDIMC + ct;
                float4 a0 = *(const float4*)p0, a1 = *(const float4*)(p0 + 4);
                float4 b0 = *(const float4*)p1, b1 = *(const float4*)(p1 + 4);
                xv[0] = a0.x - b0.x; xv[1] = a0.y - b0.y;
                xv[2] = a0.z - b0.z; xv[3] = a0.w - b0.w;
                xv[4] = a1.x - b1.x; xv[5] = a1.y - b1.y;
                xv[6] = a1.z - b1.z; xv[7] = a1.w - b1.w;
                if (addE) {
                    uint4 u = *(const uint4*)(Eb + (size_t)gr * NDIMC + ct);
                    xv[0] += __uint_as_float(u.x << 16);
                    xv[1] += __uint_as_float(u.x & 0xffff0000u);
                    xv[2] += __uint_as_float(u.y << 16);
                    xv[3] += __uint_as_float(u.y & 0xffff0000u);
                    xv[4] += __uint_as_float(u.z << 16);
                    xv[5] += __uint_as_float(u.z & 0xffff0000u);
                    xv[6] += __uint_as_float(u.w << 16);
                    xv[7] += __uint_as_float(u.w & 0xffff0000u);
                }
            } else {
#pragma unroll
                for (int t = 0; t < 8; ++t) xv[t] = 0.f;
            }
        } else {
            if (ok) {
                float4 a0 = *(const float4*)(Xf + gr * NDIMC + ct);
                float4 a1 = *(const float4*)(Xf + gr * NDIMC + ct + 4);
                xv[0] = a0.x; xv[1] = a0.y; xv[2] = a0.z; xv[3] = a0.w;
                xv[4] = a1.x; xv[5] = a1.y; xv[6] = a1.z; xv[7] = a1.w;
            } else {
#pragma unroll
                for (int t = 0; t < 8; ++t) xv[t] = 0.f;
            }
        }
#pragma unroll
        for (int t = 0; t < 8; ++t) xres[r][t] = xv[t];
        uint4 pk;
        pk.x = mgn_pk(xv[0], xv[1]); pk.y = mgn_pk(xv[2], xv[3]);
        pk.z = mgn_pk(xv[4], xv[5]); pk.w = mgn_pk(xv[6], xv[7]);
        *(uint4*)&xl[(rloc + r) * 136 + ct] = pk;
    }

    const int arow = (w * 16 + lm) * 136;     // A-frag row base (wave-private)

    for (int d = 0; d < DEPTHC; ++d) {
        // biases / LN params: 8 consecutive floats per lane -> float4 pairs
        float4 b1a = *(const float4*)(B1 + d * NDIMC + ct);
        float4 b1b = *(const float4*)(B1 + d * NDIMC + ct + 4);
        float b1v[8] = {b1a.x, b1a.y, b1a.z, b1a.w, b1b.x, b1b.y, b1b.z, b1b.w};

        // ---- GEMM1: h1 = relu(x @ W1 + b1)
        mgn_sh8 a[4];
#pragma unroll
        for (int s = 0; s < 4; ++s)
            a[s] = *(const mgn_sh8*)&xl[arow + s * 32 + q * 8];
        mgn_f32x4 acc[8];
#pragma unroll
        for (int t = 0; t < 8; ++t) acc[t] = (mgn_f32x4){0.f, 0.f, 0.f, 0.f};
        const unsigned short* p1 = PW1 + (size_t)d * 16384 + l * 8;
#pragma unroll
        for (int t = 0; t < 8; ++t)
#pragma unroll
            for (int s = 0; s < 4; ++s) {
                mgn_sh8 b = *(const mgn_sh8*)(p1 + (t * 4 + s) * 512);
                acc[t] = __builtin_amdgcn_mfma_f32_16x16x32_bf16(a[s], b, acc[t], 0, 0, 0);
            }
        // h1 -> LDS: one b128 per row (in-wave RAW ordered by lgkmcnt)
#pragma unroll
        for (int r = 0; r < 4; ++r) {
            float h1[8];
#pragma unroll
            for (int t = 0; t < 8; ++t) h1[t] = fmaxf(acc[t][r] + b1v[t], 0.f);
            uint4 pk;
            pk.x = mgn_pk(h1[0], h1[1]); pk.y = mgn_pk(h1[2], h1[3]);
            pk.z = mgn_pk(h1[4], h1[5]); pk.w = mgn_pk(h1[6], h1[7]);
            *(uint4*)&xl[(rloc + r) * 136 + ct] = pk;
        }

        float4 b2a = *(const float4*)(B2 + d * NDIMC + ct);
        float4 b2b = *(const float4*)(B2 + d * NDIMC + ct + 4);
        float4 ga  = *(const float4*)(G  + d * NDIMC + ct);
        float4 gb  = *(const float4*)(G  + d * NDIMC + ct + 4);
        float4 bta = *(const float4*)(BT + d * NDIMC + ct);
        float4 btb = *(const float4*)(BT + d * NDIMC + ct + 4);
        float b2v[8] = {b2a.x, b2a.y, b2a.z, b2a.w, b2b.x, b2b.y, b2b.z, b2b.w};
        float gv[8]  = {ga.x, ga.y, ga.z, ga.w, gb.x, gb.y, gb.z, gb.w};
        float btv[8] = {bta.x, bta.y, bta.z, bta.w, btb.x, btb.y, btb.z, btb.w};

        // ---- GEMM2: h2 = relu(h1 @ W2 + b2)
#pragma unroll
        for (int s = 0; s < 4; ++s)
            a[s] = *(const mgn_sh8*)&xl[arow + s * 32 + q * 8];
#pragma unroll
        for (int t = 0; t < 8; ++t) acc[t] = (mgn_f32x4){0.f, 0.f, 0.f, 0.f};
        const unsigned short* p2 = PW2 + (size_t)d * 16384 + l * 8;
#pragma unroll
        for (int t = 0; t < 8; ++t)
#pragma unroll
            for (int s = 0; s < 4; ++s) {
                mgn_sh8 b = *(const mgn_sh8*)(p2 + (t * 4 + s) * 512);
                acc[t] = __builtin_amdgcn_mfma_f32_16x16x32_bf16(a[s], b, acc[t], 0, 0, 0);
            }

        // ---- bias2+relu (once), LayerNorm over 128 cols, residual, new x
#pragma unroll
        for (int r = 0; r < 4; ++r) {
            float h2[8];
#pragma unroll
            for (int t = 0; t < 8; ++t) h2[t] = fmaxf(acc[t][r] + b2v[t], 0.f);
            float sum = h2[0] + h2[1] + h2[2] + h2[3] + h2[4] + h2[5] + h2[6] + h2[7];
            sum += __shfl_xor(sum, 1); sum += __shfl_xor(sum, 2);
            sum += __shfl_xor(sum, 4); sum += __shfl_xor(sum, 8);
            float mean = sum * 0.0078125f;
            float ss = 0.f;
#pragma unroll
            for (int t = 0; t < 8; ++t) {
                float dt = h2[t] - mean;
                ss = fmaf(dt, dt, ss);
            }
            ss += __shfl_xor(ss, 1); ss += __shfl_xor(ss, 2);
            ss += __shfl_xor(ss, 4); ss += __shfl_xor(ss, 8);
            float rstd = rsqrtf(ss * 0.0078125f + LNEPS);
#pragma unroll
            for (int t = 0; t < 8; ++t)
                xres[r][t] += fmaf((h2[t] - mean) * rstd, gv[t], btv[t]);
            if (d != DEPTHC - 1) {
                uint4 pk;
                pk.x = mgn_pk(xres[r][0], xres[r][1]); pk.y = mgn_pk(xres[r][2], xres[r][3]);
                pk.z = mgn_pk(xres[r][4], xres[r][5]); pk.w = mgn_pk(xres[r][6], xres[r][7]);
                *(uint4*)&xl[(rloc + r) * 136 + ct] = pk;
            }
        }
    }

    // ---- tile store
#pragma unroll
    for (int r = 0; r < 4; ++r) {
        long gr = rowbase + rloc + r;
        if (gr < nrows) {
            if (MODE == 1) {
                uint4 pk;
                pk.x = mgn_pk(xres[r][0], xres[r][1]); pk.y = mgn_pk(xres[r][2], xres[r][3]);
                pk.z = mgn_pk(xres[r][4], xres[r][5]); pk.w = mgn_pk(xres[r][6], xres[r][7]);
                *(uint4*)(Eb + (size_t)gr * NDIMC + ct) = pk;
            } else {
                float4 a0 = {xres[r][0], xres[r][1], xres[r][2], xres[r][3]};
                float4 a1 = {xres[r][4], xres[r][5], xres[r][6], xres[r][7]};
                *(float4*)(Xf + gr * NDIMC + ct)     = a0;
                *(float4*)(Xf + gr * NDIMC + ct + 4) = a1;
            }
        }
    }
}

// ---------------------------------------------------------------------------
extern "C" void kernel_launch(void* const* d_in, const int* in_sizes, int n_in,
                              void* d_out, int out_size, void* d_ws, size_t ws_size,
                              hipStream_t stream) {
    const float* v    = (const float*)d_in[0];
    const int*   ij   = (const int*)d_in[1];
    const float* encW = (const float*)d_in[2];
    const float* encB = (const float*)d_in[3];
    const float* eW1  = (const float*)d_in[4];
    const float* eB1  = (const float*)d_in[5];
    const float* eW2  = (const float*)d_in[6];
    const float* eB2  = (const float*)d_in[7];
    const float* eG   = (const float*)d_in[8];
    const float* eBT  = (const float*)d_in[9];
    const float* nW1  = (const float*)d_in[10];
    const float* nB1  = (const float*)d_in[11];
    const float* nW2  = (const float*)d_in[12];
    const float* nB2  = (const float*)d_in[13];
    const float* nG   = (const float*)d_in[14];
    const float* nBT  = (const float*)d_in[15];
    const float* decW = (const float*)d_in[16];
    const float* decB = (const float*)d_in[17];
    float* out = (float*)d_out;

    char* ws = (char*)d_ws;
    float*          h    = (float*)(ws + H_OFF);
    unsigned short* ebuf = (unsigned short*)(ws + E_OFF);
    unsigned short* pw   = (unsigned short*)(ws + PW_OFF);
    int*            flag = (int*)(ws + FLAG_OFF);

    mgn_detect_kernel<<<1, 256, 0, stream>>>(ij, flag);
    mgn_pack_kernel<<<(PWMAT + 255) / 256, 256, 0, stream>>>(eW1, pw + 0 * PWMAT);
    mgn_pack_kernel<<<(PWMAT + 255) / 256, 256, 0, stream>>>(eW2, pw + 1 * PWMAT);
    mgn_pack_kernel<<<(PWMAT + 255) / 256, 256, 0, stream>>>(nW1, pw + 2 * PWMAT);
    mgn_pack_kernel<<<(PWMAT + 255) / 256, 256, 0, stream>>>(nW2, pw + 3 * PWMAT);
    mgn_encoder_kernel<<<(NNODES * NDIMC + 255) / 256, 256, 0, stream>>>(v, encW, encB, h);

    for (int p = 0; p < NPASSESC; ++p) {
        // edge MLP with fused gather (reads h, e_prev; writes e)
        mgn_mlp6_mfma_kernel<1><<<NEDGES / 64, 256, 0, stream>>>(
            nullptr, ebuf, h, ij, flag, p > 0 ? 1 : 0, NEDGES,
            pw + 0 * PWMAT, pw + 1 * PWMAT, eB1, eB2, eG, eBT);
        // scatter e into h
        mgn_scatter_kernel<<<(int)(((long)NEDGES * NDIMC + 255) / 256), 256, 0, stream>>>(
            ebuf, ij, flag, h);
        // node MLP in-place on h
        mgn_mlp6_mfma_kernel<0><<<(NNODES + 63) / 64, 256, 0, stream>>>(
            h, nullptr, nullptr, nullptr, nullptr, 0, NNODES,
            pw + 2 * PWMAT, pw + 3 * PWMAT, nB1, nB2, nG, nBT);
    }

    mgn_decoder_kernel<<<(NNODES * NODEIN + 255) / 256, 256, 0, stream>>>(h, decW, decB, out);
}

// Round 5
// 5313.066 us; speedup vs baseline: 4.5688x; 1.0077x over previous
//
#include <hip/hip_runtime.h>
#include <hip/hip_bf16.h>
#include <cstdint>
#include <cstddef>

#define NDIMC   128
#define DEPTHC  6
#define NPASSESC 4
#define NNODES  50000
#define NEDGES  800000
#define NODEIN  5
#define LNEPS   1e-5f

// ---------------------------------------------------------------------------
// ws layout (bytes) — ~224 MiB, below proven-safe 256,000,004
#define H_OFF    0ull                     // h:  50000*128*4  = 25.6 MB fp32
#define E_OFF    25600000ull              // e:  800000*128*2 = 204.8 MB bf16
#define PW_OFF   230400000ull             // packed weights: 4 * 196,608 B bf16
#define FLAG_OFF 231186432ull
#define DEG_OFF  231186436ull             // 50001 int
#define RS_OFF   231386440ull             // rowstart: 50001 int
#define CUR_OFF  231586444ull             // cursor:   50000 int
#define EIDX_OFF 231786444ull             // eidx:     800000 int -> ends 234,986,444
#define PWMAT    98304

typedef __attribute__((ext_vector_type(8))) short mgn_sh8;
typedef __attribute__((ext_vector_type(4))) float mgn_f32x4;

// ---------------------------------------------------------------------------
__device__ __forceinline__ unsigned mgn_bf16bits(float f) {
    unsigned x = __float_as_uint(f);
    return (x + 0x7fffu + ((x >> 16) & 1u)) >> 16;   // RNE
}
__device__ __forceinline__ unsigned mgn_pk(float a, float b) {
    __hip_bfloat162 t = __float22bfloat162_rn(make_float2(a, b));
    union { __hip_bfloat162 h; unsigned u; } c; c.h = t; return c.u;
}

// ---------------------------------------------------------------------------
// flag = 1 -> ij is int32, flag = 0 -> ij is int64
__global__ void mgn_detect_kernel(const int* __restrict__ ij, int* __restrict__ flag) {
    __shared__ int any;
    if (threadIdx.x == 0) any = 0;
    __syncthreads();
    if (ij[2 * threadIdx.x + 1] != 0) atomicOr(&any, 1);
    __syncthreads();
    if (threadIdx.x == 0) *flag = any;
}

__device__ __forceinline__ long mgn_load_idx(const int* __restrict__ ij, long pos, int is32) {
    if (is32) return (long)ij[pos];
    const long long* ij8 = (const long long*)ij;
    return (long)ij8[pos];
}

// ---------------------------------------------------------------------------
// Pack fp32 row-major W[d][k][n] into MFMA B-fragment order with remapped
// output columns: n_global = (lane&15)*8 + t  (lane owns 8 consecutive cols)
__global__ void mgn_pack_kernel(const float* __restrict__ W, unsigned short* __restrict__ pw) {
    int i = blockIdx.x * blockDim.x + threadIdx.x;
    if (i >= PWMAT) return;
    int j    = i & 7;
    int lane = (i >> 3) & 63;
    int s    = (i >> 9) & 3;
    int t    = (i >> 11) & 7;
    int d    = i >> 14;
    int k = s * 32 + (lane >> 4) * 8 + j;
    int n = (lane & 15) * 8 + t;
    pw[i] = (unsigned short)mgn_bf16bits(W[(d * NDIMC + k) * NDIMC + n]);
}

// ---------------------------------------------------------------------------
// CSR build: histogram -> scan -> fill
__global__ void mgn_deg_kernel(const int* __restrict__ ij, const int* __restrict__ flag,
                               int* __restrict__ deg) {
    int e = blockIdx.x * blockDim.x + threadIdx.x;
    if (e >= NEDGES) return;
    int dst = (int)mgn_load_idx(ij, (long)NEDGES + e, *flag);
    atomicAdd(&deg[dst], 1);
}

__global__ void mgn_scan_kernel(const int* __restrict__ deg,
                                int* __restrict__ rowstart, int* __restrict__ cursor) {
    __shared__ int partial[256];
    const int tid = threadIdx.x;
    const int CH = (NNODES + 255) / 256;   // 196
    const int base = tid * CH;
    int s = 0;
    for (int i = 0; i < CH; ++i) {
        int idx = base + i;
        if (idx < NNODES) s += deg[idx];
    }
    partial[tid] = s;
    __syncthreads();
    for (int off = 1; off < 256; off <<= 1) {
        int add = (tid >= off) ? partial[tid - off] : 0;
        __syncthreads();
        partial[tid] += add;
        __syncthreads();
    }
    int run = (tid == 0) ? 0 : partial[tid - 1];
    for (int i = 0; i < CH; ++i) {
        int idx = base + i;
        if (idx < NNODES) {
            rowstart[idx] = run;
            cursor[idx]   = run;
            run += deg[idx];
        }
    }
    if (tid == 255) rowstart[NNODES] = run;
}

__global__ void mgn_fill_kernel(const int* __restrict__ ij, const int* __restrict__ flag,
                                int* __restrict__ cursor, int* __restrict__ eidx) {
    int e = blockIdx.x * blockDim.x + threadIdx.x;
    if (e >= NEDGES) return;
    int dst = (int)mgn_load_idx(ij, (long)NEDGES + e, *flag);
    int pos = atomicAdd(&cursor[dst], 1);
    eidx[pos] = e;
}

// ---------------------------------------------------------------------------
__global__ void mgn_encoder_kernel(const float* __restrict__ v,
                                   const float* __restrict__ encW,
                                   const float* __restrict__ encB,
                                   float* __restrict__ h) {
    int idx = blockIdx.x * blockDim.x + threadIdx.x;
    if (idx >= NNODES * NDIMC) return;
    int n = idx >> 7, d = idx & 127;
    float acc = encB[d];
#pragma unroll
    for (int k = 0; k < NODEIN; ++k)
        acc = fmaf(v[n * NODEIN + k], encW[k * NDIMC + d], acc);
    h[idx] = acc;
}

__global__ void mgn_decoder_kernel(const float* __restrict__ h,
                                   const float* __restrict__ decW,
                                   const float* __restrict__ decB,
                                   float* __restrict__ out) {
    int idx = blockIdx.x * blockDim.x + threadIdx.x;
    if (idx >= NNODES * NODEIN) return;
    int n = idx / NODEIN, j = idx % NODEIN;
    float acc = decB[j];
#pragma unroll 8
    for (int k = 0; k < NDIMC; ++k)
        acc = fmaf(h[n * NDIMC + k], decW[k * NODEIN + j], acc);
    out[idx] = acc;
}

// ---------------------------------------------------------------------------
// Fused 6-deep residual MLP, bf16 MFMA core, fp32 residual/LN.
// Block = 4 waves; wave w owns rows [w*16*NT, (w+1)*16*NT) — wave-private, no
// barriers. NT row-tiles per wave share each B-fragment load (halved L2 W
// traffic at NT=2). Lane lm owns global cols lm*8..+7 (b128/dwordx4 friendly).
// MODE 1 = edge: x = h[i0]-h[i1] (+ e_prev), out e (bf16).
// MODE 0 = node: x = h[row] + sum_{CSR} e[eid], out h (fp32).
template <int MODE, int NT>
__global__ __launch_bounds__(256, 2) void mgn_mlp6_mfma_kernel(
    float* __restrict__ Xf,               // node: h
    unsigned short* __restrict__ Eb,      // e buffer
    const float* __restrict__ H,          // edge: h for gather
    const int* __restrict__ ij,
    const int* __restrict__ flag,
    const int* __restrict__ rowstart,     // node CSR
    const int* __restrict__ eidx,
    int addE, int nrows,
    const unsigned short* __restrict__ PW1,
    const unsigned short* __restrict__ PW2,
    const float* __restrict__ B1, const float* __restrict__ B2,
    const float* __restrict__ G,  const float* __restrict__ BT)
{
    __shared__ unsigned short xl[NT * 64 * 136];   // row stride 136 shorts
    const int tid = threadIdx.x;
    const int w   = tid >> 6;
    const int l   = tid & 63;
    const int q   = l >> 4;
    const int lm  = l & 15;
    const int ct  = lm * 8;                        // first of lane's 8 cols
    const int wbase = w * 16 * NT;                 // wave's first local row
    const long rowbase = (long)blockIdx.x * (64 * NT);

    const int is32 = (MODE == 1) ? *flag : 0;

    // ---- tile load: xres fp32 regs (C layout) + LDS bf16 (A source)
    float xres[NT][4][8];
#pragma unroll
    for (int u = 0; u < NT; ++u) {
#pragma unroll
        for (int r = 0; r < 4; ++r) {
            const int rloc = wbase + u * 16 + q * 4 + r;
            long gr = rowbase + rloc;
            bool ok = gr < nrows;
            float xv[8];
#pragma unroll
            for (int t = 0; t < 8; ++t) xv[t] = 0.f;
            if (MODE == 1) {
                if (ok) {
                    long i0 = mgn_load_idx(ij, gr, is32);
                    long i1 = mgn_load_idx(ij, (long)NEDGES + gr, is32);
                    const float* p0 = H + i0 * NDIMC + ct;
                    const float* p1 = H + i1 * NDIMC + ct;
                    float4 a0 = *(const float4*)p0, a1 = *(const float4*)(p0 + 4);
                    float4 b0 = *(const float4*)p1, b1 = *(const float4*)(p1 + 4);
                    xv[0] = a0.x - b0.x; xv[1] = a0.y - b0.y;
                    xv[2] = a0.z - b0.z; xv[3] = a0.w - b0.w;
                    xv[4] = a1.x - b1.x; xv[5] = a1.y - b1.y;
                    xv[6] = a1.z - b1.z; xv[7] = a1.w - b1.w;
                    if (addE) {
                        uint4 u4 = *(const uint4*)(Eb + (size_t)gr * NDIMC + ct);
                        xv[0] += __uint_as_float(u4.x << 16);
                        xv[1] += __uint_as_float(u4.x & 0xffff0000u);
                        xv[2] += __uint_as_float(u4.y << 16);
                        xv[3] += __uint_as_float(u4.y & 0xffff0000u);
                        xv[4] += __uint_as_float(u4.z << 16);
                        xv[5] += __uint_as_float(u4.z & 0xffff0000u);
                        xv[6] += __uint_as_float(u4.w << 16);
                        xv[7] += __uint_as_float(u4.w & 0xffff0000u);
                    }
                }
            } else {
                if (ok) {
                    float4 a0 = *(const float4*)(Xf + gr * NDIMC + ct);
                    float4 a1 = *(const float4*)(Xf + gr * NDIMC + ct + 4);
                    xv[0] = a0.x; xv[1] = a0.y; xv[2] = a0.z; xv[3] = a0.w;
                    xv[4] = a1.x; xv[5] = a1.y; xv[6] = a1.z; xv[7] = a1.w;
                    // CSR aggregate: bounds uniform across the 16 lanes of quad
                    int rs = rowstart[gr], re = rowstart[gr + 1];
                    for (int k = rs; k < re; ++k) {
                        int eid = eidx[k];
                        uint4 u4 = *(const uint4*)(Eb + (size_t)eid * NDIMC + ct);
                        xv[0] += __uint_as_float(u4.x << 16);
                        xv[1] += __uint_as_float(u4.x & 0xffff0000u);
                        xv[2] += __uint_as_float(u4.y << 16);
                        xv[3] += __uint_as_float(u4.y & 0xffff0000u);
                        xv[4] += __uint_as_float(u4.z << 16);
                        xv[5] += __uint_as_float(u4.z & 0xffff0000u);
                        xv[6] += __uint_as_float(u4.w << 16);
                        xv[7] += __uint_as_float(u4.w & 0xffff0000u);
                    }
                }
            }
#pragma unroll
            for (int t = 0; t < 8; ++t) xres[u][r][t] = xv[t];
            uint4 pk;
            pk.x = mgn_pk(xv[0], xv[1]); pk.y = mgn_pk(xv[2], xv[3]);
            pk.z = mgn_pk(xv[4], xv[5]); pk.w = mgn_pk(xv[6], xv[7]);
            *(uint4*)&xl[rloc * 136 + ct] = pk;
        }
    }

    for (int d = 0; d < DEPTHC; ++d) {
        float4 b1a = *(const float4*)(B1 + d * NDIMC + ct);
        float4 b1b = *(const float4*)(B1 + d * NDIMC + ct + 4);
        float b1v[8] = {b1a.x, b1a.y, b1a.z, b1a.w, b1b.x, b1b.y, b1b.z, b1b.w};

        // ---- GEMM1: h1 = relu(x @ W1 + b1)
        mgn_sh8 a[NT][4];
#pragma unroll
        for (int u = 0; u < NT; ++u)
#pragma unroll
            for (int s = 0; s < 4; ++s)
                a[u][s] = *(const mgn_sh8*)&xl[(wbase + u * 16 + lm) * 136 + s * 32 + q * 8];
        mgn_f32x4 acc[NT][8];
#pragma unroll
        for (int u = 0; u < NT; ++u)
#pragma unroll
            for (int t = 0; t < 8; ++t) acc[u][t] = (mgn_f32x4){0.f, 0.f, 0.f, 0.f};
        const unsigned short* p1 = PW1 + (size_t)d * 16384 + l * 8;
#pragma unroll
        for (int t = 0; t < 8; ++t)
#pragma unroll
            for (int s = 0; s < 4; ++s) {
                mgn_sh8 b = *(const mgn_sh8*)(p1 + (t * 4 + s) * 512);
#pragma unroll
                for (int u = 0; u < NT; ++u)
                    acc[u][t] = __builtin_amdgcn_mfma_f32_16x16x32_bf16(a[u][s], b, acc[u][t], 0, 0, 0);
            }
        // h1 -> LDS (own rows; in-wave RAW ordered by lgkmcnt)
#pragma unroll
        for (int u = 0; u < NT; ++u)
#pragma unroll
            for (int r = 0; r < 4; ++r) {
                const int rloc = wbase + u * 16 + q * 4 + r;
                float h1[8];
#pragma unroll
                for (int t = 0; t < 8; ++t) h1[t] = fmaxf(acc[u][t][r] + b1v[t], 0.f);
                uint4 pk;
                pk.x = mgn_pk(h1[0], h1[1]); pk.y = mgn_pk(h1[2], h1[3]);
                pk.z = mgn_pk(h1[4], h1[5]); pk.w = mgn_pk(h1[6], h1[7]);
                *(uint4*)&xl[rloc * 136 + ct] = pk;
            }

        float4 b2a = *(const float4*)(B2 + d * NDIMC + ct);
        float4 b2b = *(const float4*)(B2 + d * NDIMC + ct + 4);
        float4 ga  = *(const float4*)(G  + d * NDIMC + ct);
        float4 gb  = *(const float4*)(G  + d * NDIMC + ct + 4);
        float4 bta = *(const float4*)(BT + d * NDIMC + ct);
        float4 btb = *(const float4*)(BT + d * NDIMC + ct + 4);
        float b2v[8] = {b2a.x, b2a.y, b2a.z, b2a.w, b2b.x, b2b.y, b2b.z, b2b.w};
        float gv[8]  = {ga.x, ga.y, ga.z, ga.w, gb.x, gb.y, gb.z, gb.w};
        float btv[8] = {bta.x, bta.y, bta.z, bta.w, btb.x, btb.y, btb.z, btb.w};

        // ---- GEMM2: h2 = relu(h1 @ W2 + b2)
#pragma unroll
        for (int u = 0; u < NT; ++u)
#pragma unroll
            for (int s = 0; s < 4; ++s)
                a[u][s] = *(const mgn_sh8*)&xl[(wbase + u * 16 + lm) * 136 + s * 32 + q * 8];
#pragma unroll
        for (int u = 0; u < NT; ++u)
#pragma unroll
            for (int t = 0; t < 8; ++t) acc[u][t] = (mgn_f32x4){0.f, 0.f, 0.f, 0.f};
        const unsigned short* p2 = PW2 + (size_t)d * 16384 + l * 8;
#pragma unroll
        for (int t = 0; t < 8; ++t)
#pragma unroll
            for (int s = 0; s < 4; ++s) {
                mgn_sh8 b = *(const mgn_sh8*)(p2 + (t * 4 + s) * 512);
#pragma unroll
                for (int u = 0; u < NT; ++u)
                    acc[u][t] = __builtin_amdgcn_mfma_f32_16x16x32_bf16(a[u][s], b, acc[u][t], 0, 0, 0);
            }

        // ---- bias2+relu, LayerNorm over 128 cols, residual, write new x
#pragma unroll
        for (int u = 0; u < NT; ++u)
#pragma unroll
            for (int r = 0; r < 4; ++r) {
                const int rloc = wbase + u * 16 + q * 4 + r;
                float h2[8];
#pragma unroll
                for (int t = 0; t < 8; ++t) h2[t] = fmaxf(acc[u][t][r] + b2v[t], 0.f);
                float sum = h2[0] + h2[1] + h2[2] + h2[3] + h2[4] + h2[5] + h2[6] + h2[7];
                sum += __shfl_xor(sum, 1); sum += __shfl_xor(sum, 2);
                sum += __shfl_xor(sum, 4); sum += __shfl_xor(sum, 8);
                float mean = sum * 0.0078125f;
                float ss = 0.f;
#pragma unroll
                for (int t = 0; t < 8; ++t) {
                    float dt = h2[t] - mean;
                    ss = fmaf(dt, dt, ss);
                }
                ss += __shfl_xor(ss, 1); ss += __shfl_xor(ss, 2);
                ss += __shfl_xor(ss, 4); ss += __shfl_xor(ss, 8);
                float rstd = rsqrtf(ss * 0.0078125f + LNEPS);
#pragma unroll
                for (int t = 0; t < 8; ++t)
                    xres[u][r][t] += fmaf((h2[t] - mean) * rstd, gv[t], btv[t]);
                if (d != DEPTHC - 1) {
                    uint4 pk;
                    pk.x = mgn_pk(xres[u][r][0], xres[u][r][1]);
                    pk.y = mgn_pk(xres[u][r][2], xres[u][r][3]);
                    pk.z = mgn_pk(xres[u][r][4], xres[u][r][5]);
                    pk.w = mgn_pk(xres[u][r][6], xres[u][r][7]);
                    *(uint4*)&xl[rloc * 136 + ct] = pk;
                }
            }
    }

    // ---- tile store
#pragma unroll
    for (int u = 0; u < NT; ++u)
#pragma unroll
        for (int r = 0; r < 4; ++r) {
            const int rloc = wbase + u * 16 + q * 4 + r;
            long gr = rowbase + rloc;
            if (gr < nrows) {
                if (MODE == 1) {
                    uint4 pk;
                    pk.x = mgn_pk(xres[u][r][0], xres[u][r][1]);
                    pk.y = mgn_pk(xres[u][r][2], xres[u][r][3]);
                    pk.z = mgn_pk(xres[u][r][4], xres[u][r][5]);
                    pk.w = mgn_pk(xres[u][r][6], xres[u][r][7]);
                    *(uint4*)(Eb + (size_t)gr * NDIMC + ct) = pk;
                } else {
                    float4 a0 = {xres[u][r][0], xres[u][r][1], xres[u][r][2], xres[u][r][3]};
                    float4 a1 = {xres[u][r][4], xres[u][r][5], xres[u][r][6], xres[u][r][7]};
                    *(float4*)(Xf + gr * NDIMC + ct)     = a0;
                    *(float4*)(Xf + gr * NDIMC + ct + 4) = a1;
                }
            }
        }
}

// ---------------------------------------------------------------------------
extern "C" void kernel_launch(void* const* d_in, const int* in_sizes, int n_in,
                              void* d_out, int out_size, void* d_ws, size_t ws_size,
                              hipStream_t stream) {
    const float* v    = (const float*)d_in[0];
    const int*   ij   = (const int*)d_in[1];
    const float* encW = (const float*)d_in[2];
    const float* encB = (const float*)d_in[3];
    const float* eW1  = (const float*)d_in[4];
    const float* eB1  = (const float*)d_in[5];
    const float* eW2  = (const float*)d_in[6];
    const float* eB2  = (const float*)d_in[7];
    const float* eG   = (const float*)d_in[8];
    const float* eBT  = (const float*)d_in[9];
    const float* nW1  = (const float*)d_in[10];
    const float* nB1  = (const float*)d_in[11];
    const float* nW2  = (const float*)d_in[12];
    const float* nB2  = (const float*)d_in[13];
    const float* nG   = (const float*)d_in[14];
    const float* nBT  = (const float*)d_in[15];
    const float* decW = (const float*)d_in[16];
    const float* decB = (const float*)d_in[17];
    float* out = (float*)d_out;

    char* ws = (char*)d_ws;
    float*          h    = (float*)(ws + H_OFF);
    unsigned short* ebuf = (unsigned short*)(ws + E_OFF);
    unsigned short* pw   = (unsigned short*)(ws + PW_OFF);
    int*            flag = (int*)(ws + FLAG_OFF);
    int*            deg  = (int*)(ws + DEG_OFF);
    int*            rstt = (int*)(ws + RS_OFF);
    int*            curs = (int*)(ws + CUR_OFF);
    int*            eidx = (int*)(ws + EIDX_OFF);

    mgn_detect_kernel<<<1, 256, 0, stream>>>(ij, flag);
    mgn_pack_kernel<<<(PWMAT + 255) / 256, 256, 0, stream>>>(eW1, pw + 0 * PWMAT);
    mgn_pack_kernel<<<(PWMAT + 255) / 256, 256, 0, stream>>>(eW2, pw + 1 * PWMAT);
    mgn_pack_kernel<<<(PWMAT + 255) / 256, 256, 0, stream>>>(nW1, pw + 2 * PWMAT);
    mgn_pack_kernel<<<(PWMAT + 255) / 256, 256, 0, stream>>>(nW2, pw + 3 * PWMAT);

    // CSR build (static graph; rebuilt every call for graph-capture safety)
    hipMemsetAsync(deg, 0, (size_t)(NNODES + 1) * sizeof(int), stream);
    mgn_deg_kernel<<<(NEDGES + 255) / 256, 256, 0, stream>>>(ij, flag, deg);
    mgn_scan_kernel<<<1, 256, 0, stream>>>(deg, rstt, curs);
    mgn_fill_kernel<<<(NEDGES + 255) / 256, 256, 0, stream>>>(ij, flag, curs, eidx);

    mgn_encoder_kernel<<<(NNODES * NDIMC + 255) / 256, 256, 0, stream>>>(v, encW, encB, h);

    for (int p = 0; p < NPASSESC; ++p) {
        // edge MLP (fused gather; NT=2 -> 128 rows/block)
        mgn_mlp6_mfma_kernel<1, 2><<<NEDGES / 128, 256, 0, stream>>>(
            nullptr, ebuf, h, ij, flag, nullptr, nullptr, p > 0 ? 1 : 0, NEDGES,
            pw + 0 * PWMAT, pw + 1 * PWMAT, eB1, eB2, eG, eBT);
        // node MLP with fused CSR aggregation (NT=1 -> 64 rows/block)
        mgn_mlp6_mfma_kernel<0, 1><<<(NNODES + 63) / 64, 256, 0, stream>>>(
            h, ebuf, nullptr, nullptr, nullptr, rstt, eidx, 0, NNODES,
            pw + 2 * PWMAT, pw + 3 * PWMAT, nB1, nB2, nG, nBT);
    }

    mgn_decoder_kernel<<<(NNODES * NODEIN + 255) / 256, 256, 0, stream>>>(h, decW, decB, out);
}